// Round 7
// baseline (3316.707 us; speedup 1.0000x reference)
//
#include <hip/hip_runtime.h>

typedef __bf16 bf16;
typedef __bf16 bf16x8 __attribute__((ext_vector_type(8)));
typedef float f32x4 __attribute__((ext_vector_type(4)));
typedef unsigned long long u64;

#define T_LEN 512
#define BATCH 64
#define HID 256
#define LDA 528   // bf16 row stride: 264 dw % 32 = 8 -> 2-way (free) b128 banks
#define ZLD 68

#define POISON 0xAAAAAAAAAAAAAAAAull

// workspace layout (~1.7 MB)
#define CTRL_BYTES 4096
#define HSLOT_U64 4096                       // 32 KB: 64 b x 256 hid x bf16
#define NSLOT 8
#define H1_OFF CTRL_BYTES
#define HBUF_BYTES (2 * NSLOT * HSLOT_U64 * 8)   // 2 dirs x 8 slots = 512 KB
#define H2_OFF (H1_OFF + HBUF_BYTES)
#define LOG_OFF (H2_OFF + HBUF_BYTES)
#define LOG_BYTES (T_LEN * BATCH * 5 * 4)

// LDS layout
#define SMEM_A (64 * LDA * 2)     // 67584
#define SMEM_Z (64 * ZLD * 4)     // 17408
#define SMEM_C 4096
#define SMEM_TAIL 576
#define SMEM_BYTES (SMEM_A + SMEM_Z + SMEM_C + SMEM_TAIL)   // 89664

__device__ inline uint4 cvt8(const float4* s) {
    float4 a = s[0], b = s[1];
    union { uint4 u; bf16 h[8]; } r;
    r.h[0] = (bf16)a.x; r.h[1] = (bf16)a.y; r.h[2] = (bf16)a.z; r.h[3] = (bf16)a.w;
    r.h[4] = (bf16)b.x; r.h[5] = (bf16)b.y; r.h[6] = (bf16)b.z; r.h[7] = (bf16)b.w;
    return r.u;
}

// batched poll: issue all 16, then fix stragglers (valid iff != POISON)
__device__ inline void poll16(const u64* base, int tid, u64* v) {
#pragma unroll
    for (int k = 0; k < 16; ++k)
        v[k] = __hip_atomic_load(base + k * 256 + tid, __ATOMIC_RELAXED, __HIP_MEMORY_SCOPE_AGENT);
#pragma unroll
    for (int k = 0; k < 16; ++k)
        while (v[k] == POISON)
            v[k] = __hip_atomic_load(base + k * 256 + tid, __ATOMIC_RELAXED, __HIP_MEMORY_SCOPE_AGENT);
}

__global__ void __launch_bounds__(256, 1)
lstm_kernel(const int* __restrict__ tokens,
            const float* __restrict__ embed,
            const float* __restrict__ W1f, const float* __restrict__ U1f, const float* __restrict__ b1f,
            const float* __restrict__ W2f, const float* __restrict__ U2f, const float* __restrict__ b2f,
            const float* __restrict__ W1b, const float* __restrict__ U1b, const float* __restrict__ b1b,
            const float* __restrict__ W2b, const float* __restrict__ U2b, const float* __restrict__ b2b,
            const float* __restrict__ dW,
            char* __restrict__ ws)
{
    extern __shared__ char smem[];
    bf16*  Abuf  = (bf16*)smem;
    float* zLds  = (float*)(smem + SMEM_A);
    float* cLds  = (float*)(smem + SMEM_A + SMEM_Z);
    float* bLds  = (float*)(smem + SMEM_A + SMEM_Z + SMEM_C);
    float* dwLds = bLds + 64;

    const int tid = threadIdx.x;
    const int wg  = blockIdx.x;
    // XCD co-location: 16 WGs of one (dir,layer) land on blockIdx == {c, c+4} mod 8
    const int dir = wg & 1, layer = (wg >> 1) & 1, sub = wg >> 2;

    const float *Wp, *Up, *bp;
    if (dir == 0) { if (layer == 0) { Wp=W1f; Up=U1f; bp=b1f; } else { Wp=W2f; Up=U2f; bp=b2f; } }
    else          { if (layer == 0) { Wp=W1b; Up=U1b; bp=b1b; } else { Wp=W2b; Up=U2b; bp=b2b; } }

    // ---- stage this WG's 64 gate-columns of [W;U] transposed into Abuf as bf16 ----
    {
        for (int it = 0; it < 32; ++it) {
            int idx = it * 256 + tid;
            int k = idx >> 4, q4 = idx & 15;
            int g = q4 >> 2, u0 = (q4 & 3) * 4;
            const float* src = (k < 256) ? (Wp + (size_t)k * 1024 + g * 256 + sub * 16 + u0)
                                         : (Up + (size_t)(k - 256) * 1024 + g * 256 + sub * 16 + u0);
            float4 v = *(const float4*)src;
            int c0 = g * 16 + u0;
            Abuf[(c0 + 0) * LDA + k] = (bf16)v.x;
            Abuf[(c0 + 1) * LDA + k] = (bf16)v.y;
            Abuf[(c0 + 2) * LDA + k] = (bf16)v.z;
            Abuf[(c0 + 3) * LDA + k] = (bf16)v.w;
        }
        if (tid < 64) {
            int g = tid >> 4, u = tid & 15;
            bLds[tid] = bp[g * 256 + sub * 16 + u];
        }
        if (tid < 80) {
            int u = tid / 5, c = tid % 5;
            dwLds[tid] = dW[(size_t)(dir * 256 + sub * 16 + u) * 5 + c];
        }
        for (int i = tid; i < 1024; i += 256) cLds[i] = 0.f;
    }
    __syncthreads();

    // ---- pin B fragments: wave covers a 32x32 quadrant of the 64x64 z tile ----
    const int wave = tid >> 6, lane = tid & 63, quad = lane >> 4, ln = lane & 15;
    const int mrow0 = (wave >> 1) * 32, ncol0 = (wave & 1) * 32;
    bf16x8 bfrag[2][16];
#pragma unroll
    for (int nt = 0; nt < 2; ++nt)
#pragma unroll
        for (int kt = 0; kt < 16; ++kt)
            bfrag[nt][kt] = *(const bf16x8*)&Abuf[(ncol0 + nt * 16 + ln) * LDA + kt * 32 + quad * 8];
    __syncthreads();

    u64* h1buf = (u64*)(ws + H1_OFF) + (size_t)dir * NSLOT * HSLOT_U64;
    u64* h2buf = (u64*)(ws + H2_OFF) + (size_t)dir * NSLOT * HSLOT_U64;
    u64* hOwn  = (layer == 0) ? h1buf : h2buf;
    float* logits = (float*)(ws + LOG_OFF);
    unsigned* ctrL2 = (unsigned*)ws + dir * 32;   // only L2 increments; L1 throttles on it

    const int bA = tid >> 2, qA = tid & 3;

    // ---- embed/token software pipeline state (layer 0 only) ----
    float4 pf[16];
    int tokB = 0;
    if (layer == 0) {
        const int tt0 = dir ? (T_LEN - 1) : 0;
        int tokA = tokens[bA * T_LEN + tt0];
        const float4* src = (const float4*)(embed + (size_t)tokA * HID + qA * 64);
#pragma unroll
        for (int j = 0; j < 16; ++j) pf[j] = src[j];
        const int tt1 = dir ? (T_LEN - 2) : 1;
        tokB = tokens[bA * T_LEN + tt1];
    }

    for (int s = 0; s < T_LEN; ++s) {
        // ---- L1 run-ahead throttle (lagging, off critical path in steady state) ----
        if (layer == 0 && tid == 0 && s >= 6) {
            unsigned need = (unsigned)(s - 5) * 16u;
            while (__hip_atomic_load(ctrL2, __ATOMIC_RELAXED, __HIP_MEMORY_SCOPE_AGENT) < need)
                __builtin_amdgcn_s_sleep(1);
        }

        // ---- poll own h (self-validating data; slot s%8 = h_s) ----
        u64 hreg[16];
        poll16(hOwn + (size_t)(s & 7) * HSLOT_U64, tid, hreg);

        // ---- x part ----
        if (layer == 0) {
            uint4* dstx = (uint4*)&Abuf[bA * LDA + qA * 64];
#pragma unroll
            for (int j = 0; j < 8; ++j) dstx[j] = cvt8(&pf[2 * j]);
        } else {
            u64 xreg[16];
            poll16(h1buf + (size_t)((s + 1) & 7) * HSLOT_U64, tid, xreg);   // x(s) = h1_{s+1}
#pragma unroll
            for (int k = 0; k < 16; ++k)
                *(u64*)&Abuf[bA * LDA + k * 16 + qA * 4] = xreg[k];
        }
#pragma unroll
        for (int k = 0; k < 16; ++k)
            *(u64*)&Abuf[bA * LDA + 256 + k * 16 + qA * 4] = hreg[k];
        __syncthreads();

        // ---- prefetch embed for step s+1 (RT hidden under GEMM) ----
        if (layer == 0) {
            const float4* src = (const float4*)(embed + (size_t)tokB * HID + qA * 64);
#pragma unroll
            for (int j = 0; j < 16; ++j) pf[j] = src[j];
            const int sn2 = (s + 2 < T_LEN) ? s + 2 : T_LEN - 1;
            const int tt2 = dir ? (T_LEN - 1 - sn2) : sn2;
            tokB = tokens[bA * T_LEN + tt2];
        }

        // ---- GEMM: z[64x64] = A[64x512] @ Wt^T ----
        f32x4 acc[2][2];
#pragma unroll
        for (int mi = 0; mi < 2; ++mi)
#pragma unroll
            for (int ni = 0; ni < 2; ++ni) acc[mi][ni] = (f32x4)(0.0f);
#pragma unroll
        for (int kt = 0; kt < 16; ++kt) {
            bf16x8 a0 = *(const bf16x8*)&Abuf[(mrow0 + ln) * LDA + kt * 32 + quad * 8];
            bf16x8 a1 = *(const bf16x8*)&Abuf[(mrow0 + 16 + ln) * LDA + kt * 32 + quad * 8];
            acc[0][0] = __builtin_amdgcn_mfma_f32_16x16x32_bf16(a0, bfrag[0][kt], acc[0][0], 0, 0, 0);
            acc[0][1] = __builtin_amdgcn_mfma_f32_16x16x32_bf16(a0, bfrag[1][kt], acc[0][1], 0, 0, 0);
            acc[1][0] = __builtin_amdgcn_mfma_f32_16x16x32_bf16(a1, bfrag[0][kt], acc[1][0], 0, 0, 0);
            acc[1][1] = __builtin_amdgcn_mfma_f32_16x16x32_bf16(a1, bfrag[1][kt], acc[1][1], 0, 0, 0);
        }
#pragma unroll
        for (int mi = 0; mi < 2; ++mi)
#pragma unroll
            for (int ni = 0; ni < 2; ++ni) {
                int row = mrow0 + mi * 16 + quad * 4;
                int col = ncol0 + ni * 16 + ln;
#pragma unroll
                for (int r = 0; r < 4; ++r)
                    zLds[(row + r) * ZLD + col] = acc[mi][ni][r];
            }
        __syncthreads();

        // ---- gates ----
        // Drain: orders previous step's poison-clear before this step's h-write.
        // Everything outstanding here is already-consumed loads / old stores -> ~free.
        asm volatile("s_waitcnt vmcnt(0)" ::: "memory");

        u64* hdst = hOwn + (size_t)((s + 1) & 7) * HSLOT_U64;
        u64* hclr = hOwn + (size_t)((s + 3) & 7) * HSLOT_U64;
        float hv[4];
        {
            const int b = bA, u0 = qA * 4;
#pragma unroll
            for (int e = 0; e < 4; ++e) {
                int u = u0 + e;
                float zi = zLds[b * ZLD + u]      + bLds[u];
                float zf = zLds[b * ZLD + 16 + u] + bLds[16 + u];
                float zg = zLds[b * ZLD + 32 + u] + bLds[32 + u];
                float zo = zLds[b * ZLD + 48 + u] + bLds[48 + u];
                float ig = 1.f / (1.f + __expf(-zi));
                float fg = 1.f / (1.f + __expf(-zf));
                float gg = 1.f - 2.f / (__expf(2.f * zg) + 1.f);
                float og = 1.f / (1.f + __expf(-zo));
                float cn = fg * cLds[b * 16 + u] + ig * gg;
                cLds[b * 16 + u] = cn;
                hv[e] = og * (1.f - 2.f / (__expf(2.f * cn) + 1.f));
            }
            union { u64 w; bf16 h[4]; } pk;
#pragma unroll
            for (int e = 0; e < 4; ++e) pk.h[e] = (bf16)hv[e];
            __hip_atomic_store(hdst + sub * 256 + tid, pk.w,
                               __ATOMIC_RELAXED, __HIP_MEMORY_SCOPE_AGENT);
            // re-poison future slot (own slice); per-location program order vs later rewrite
            __hip_atomic_store(hclr + sub * 256 + tid, POISON,
                               __ATOMIC_RELAXED, __HIP_MEMORY_SCOPE_AGENT);
        }
        if (layer == 1) {
            float pr[5];
#pragma unroll
            for (int c = 0; c < 5; ++c)
                pr[c] = hv[0] * dwLds[(qA * 4 + 0) * 5 + c] + hv[1] * dwLds[(qA * 4 + 1) * 5 + c]
                      + hv[2] * dwLds[(qA * 4 + 2) * 5 + c] + hv[3] * dwLds[(qA * 4 + 3) * 5 + c];
#pragma unroll
            for (int m = 1; m < 4; m <<= 1)
#pragma unroll
                for (int c = 0; c < 5; ++c) pr[c] += __shfl_xor(pr[c], m);
            if (qA == 0) {
                const int tp = dir ? (T_LEN - 1 - s) : s;
                float* lp = &logits[((size_t)tp * BATCH + bA) * 5];
#pragma unroll
                for (int c = 0; c < 5; ++c) atomicAdd(lp + c, pr[c]);
            }
        }

        __syncthreads();   // all consumed x/h + cLds settled before publish & next iter
        if (layer == 1 && tid == 0)
            __hip_atomic_fetch_add(ctrL2, 1u, __ATOMIC_RELAXED, __HIP_MEMORY_SCOPE_AGENT);
    }
}

__global__ void __launch_bounds__(256)
softmax_kernel(const char* __restrict__ ws, const float* __restrict__ dB, float* __restrict__ out)
{
    const int gid = blockIdx.x * 256 + threadIdx.x;
    const int b = gid & 63, t = gid >> 6;
    const float* lp = (const float*)(ws + LOG_OFF) + ((size_t)t * BATCH + b) * 5;
    float l[5];
#pragma unroll
    for (int c = 0; c < 5; ++c) l[c] = lp[c] + dB[c];
    float m = l[0];
#pragma unroll
    for (int c = 1; c < 5; ++c) m = fmaxf(m, l[c]);
    float e[5], ssum = 0.f;
#pragma unroll
    for (int c = 0; c < 5; ++c) { e[c] = __expf(l[c] - m); ssum += e[c]; }
    float inv = 1.f / ssum;
    float* o = out + ((size_t)b * T_LEN + t) * 5;
#pragma unroll
    for (int c = 0; c < 5; ++c) o[c] = e[c] * inv;
}

extern "C" void kernel_launch(void* const* d_in, const int* in_sizes, int n_in,
                              void* d_out, int out_size, void* d_ws, size_t ws_size,
                              hipStream_t stream)
{
    const int*   tokens = (const int*)d_in[0];
    const float* embed  = (const float*)d_in[1];
    const float* W1f = (const float*)d_in[2],  *U1f = (const float*)d_in[3],  *b1f = (const float*)d_in[4];
    const float* W2f = (const float*)d_in[5],  *U2f = (const float*)d_in[6],  *b2f = (const float*)d_in[7];
    const float* W1b = (const float*)d_in[8],  *U1b = (const float*)d_in[9],  *b1b = (const float*)d_in[10];
    const float* W2b = (const float*)d_in[11], *U2b = (const float*)d_in[12], *b2b = (const float*)d_in[13];
    const float* dW  = (const float*)d_in[14], *dB  = (const float*)d_in[15];

    const size_t DIRB = (size_t)NSLOT * HSLOT_U64 * 8;   // per-dir h buffer bytes
    char* w = (char*)d_ws;
    hipMemsetAsync(w, 0, CTRL_BYTES, stream);                      // counters
    hipMemsetAsync(w + H1_OFF, 0xAA, 2 * HBUF_BYTES, stream);      // poison all h slots
    hipMemsetAsync(w + H1_OFF + 0 * DIRB, 0, HSLOT_U64 * 8, stream);   // h1 dir0 slot0 = h_0 = 0
    hipMemsetAsync(w + H1_OFF + 1 * DIRB, 0, HSLOT_U64 * 8, stream);   // h1 dir1 slot0
    hipMemsetAsync(w + H2_OFF + 0 * DIRB, 0, HSLOT_U64 * 8, stream);   // h2 dir0 slot0
    hipMemsetAsync(w + H2_OFF + 1 * DIRB, 0, HSLOT_U64 * 8, stream);   // h2 dir1 slot0
    hipMemsetAsync(w + LOG_OFF, 0, LOG_BYTES, stream);             // logits

    hipFuncSetAttribute(reinterpret_cast<const void*>(lstm_kernel),
                        hipFuncAttributeMaxDynamicSharedMemorySize, SMEM_BYTES);
    lstm_kernel<<<dim3(64), dim3(256), SMEM_BYTES, stream>>>(
        tokens, embed, W1f, U1f, b1f, W2f, U2f, b2f,
        W1b, U1b, b1b, W2b, U2b, b2b, dW, (char*)d_ws);
    softmax_kernel<<<dim3(128), dim3(256), 0, stream>>>((const char*)d_ws, dB, (float*)d_out);
}

// Round 8
// 3264.564 us; speedup vs baseline: 1.0160x; 1.0160x over previous
//
#include <hip/hip_runtime.h>

typedef __bf16 bf16;
typedef __bf16 bf16x8 __attribute__((ext_vector_type(8)));
typedef float f32x4 __attribute__((ext_vector_type(4)));
typedef unsigned long long u64;

#define T_LEN 512
#define BATCH 64
#define HID 256
#define LDA 528   // bf16 row stride: 2-way (free) b128 bank pattern
#define ZLD 68

#define POISON 0xAAAAAAAAAAAAAAAAull

// workspace layout (~1.7 MB)
#define CTRL_BYTES 4096
#define HSLOT_U64 4096                       // 32 KB: 64 b x 256 hid x bf16
#define NSLOT 8
#define H1_OFF CTRL_BYTES
#define HBUF_BYTES (2 * NSLOT * HSLOT_U64 * 8)   // 2 dirs x 8 slots = 512 KB
#define H2_OFF (H1_OFF + HBUF_BYTES)
#define LOG_OFF (H2_OFF + HBUF_BYTES)
#define LOG_BYTES (T_LEN * BATCH * 5 * 4)

// LDS layout
#define SMEM_A (64 * LDA * 2)     // 67584
#define SMEM_Z (64 * ZLD * 4)     // 17408
#define SMEM_C 4096
#define SMEM_TAIL 576
#define SMEM_BYTES (SMEM_A + SMEM_Z + SMEM_C + SMEM_TAIL)   // 89664

// LDS-only barrier: does NOT drain vmcnt -> global prefetches stay in flight
#define BARRIER() asm volatile("s_waitcnt lgkmcnt(0)\n\ts_barrier" ::: "memory")

__device__ inline uint4 cvt8(const float4* s) {
    float4 a = s[0], b = s[1];
    union { uint4 u; bf16 h[8]; } r;
    r.h[0] = (bf16)a.x; r.h[1] = (bf16)a.y; r.h[2] = (bf16)a.z; r.h[3] = (bf16)a.w;
    r.h[4] = (bf16)b.x; r.h[5] = (bf16)b.y; r.h[6] = (bf16)b.z; r.h[7] = (bf16)b.w;
    return r.u;
}

// batched poll: each retry round re-issues ALL missing words back-to-back,
// then waits once -> 1 round-trip per round (not per word)
__device__ inline void poll16(const u64* base, int tid, u64* v) {
#pragma unroll
    for (int k = 0; k < 16; ++k)
        v[k] = __hip_atomic_load(base + k * 256 + tid, __ATOMIC_RELAXED, __HIP_MEMORY_SCOPE_AGENT);
    for (;;) {
        bool any = false;
#pragma unroll
        for (int k = 0; k < 16; ++k) any |= (v[k] == POISON);
        if (!any) break;
#pragma unroll
        for (int k = 0; k < 16; ++k)
            if (v[k] == POISON)
                v[k] = __hip_atomic_load(base + k * 256 + tid, __ATOMIC_RELAXED, __HIP_MEMORY_SCOPE_AGENT);
    }
}

__global__ void __launch_bounds__(256, 1)
lstm_kernel(const int* __restrict__ tokens,
            const float* __restrict__ embed,
            const float* __restrict__ W1f, const float* __restrict__ U1f, const float* __restrict__ b1f,
            const float* __restrict__ W2f, const float* __restrict__ U2f, const float* __restrict__ b2f,
            const float* __restrict__ W1b, const float* __restrict__ U1b, const float* __restrict__ b1b,
            const float* __restrict__ W2b, const float* __restrict__ U2b, const float* __restrict__ b2b,
            const float* __restrict__ dW,
            char* __restrict__ ws)
{
    extern __shared__ char smem[];
    bf16*  Abuf  = (bf16*)smem;
    float* zLds  = (float*)(smem + SMEM_A);
    float* cLds  = (float*)(smem + SMEM_A + SMEM_Z);
    float* bLds  = (float*)(smem + SMEM_A + SMEM_Z + SMEM_C);
    float* dwLds = bLds + 64;

    const int tid = threadIdx.x;
    const int wg  = blockIdx.x;
    const int dir = wg & 1, layer = (wg >> 1) & 1, sub = wg >> 2;

    const float *Wp, *Up, *bp;
    if (dir == 0) { if (layer == 0) { Wp=W1f; Up=U1f; bp=b1f; } else { Wp=W2f; Up=U2f; bp=b2f; } }
    else          { if (layer == 0) { Wp=W1b; Up=U1b; bp=b1b; } else { Wp=W2b; Up=U2b; bp=b2b; } }

    // ---- stage this WG's 64 gate-columns of [W;U] transposed into Abuf as bf16 ----
    {
        for (int it = 0; it < 32; ++it) {
            int idx = it * 256 + tid;
            int k = idx >> 4, q4 = idx & 15;
            int g = q4 >> 2, u0 = (q4 & 3) * 4;
            const float* src = (k < 256) ? (Wp + (size_t)k * 1024 + g * 256 + sub * 16 + u0)
                                         : (Up + (size_t)(k - 256) * 1024 + g * 256 + sub * 16 + u0);
            float4 v = *(const float4*)src;
            int c0 = g * 16 + u0;
            Abuf[(c0 + 0) * LDA + k] = (bf16)v.x;
            Abuf[(c0 + 1) * LDA + k] = (bf16)v.y;
            Abuf[(c0 + 2) * LDA + k] = (bf16)v.z;
            Abuf[(c0 + 3) * LDA + k] = (bf16)v.w;
        }
        if (tid < 64) {
            int g = tid >> 4, u = tid & 15;
            bLds[tid] = bp[g * 256 + sub * 16 + u];
        }
        if (tid < 80) {
            int u = tid / 5, c = tid % 5;
            dwLds[tid] = dW[(size_t)(dir * 256 + sub * 16 + u) * 5 + c];
        }
        for (int i = tid; i < 1024; i += 256) cLds[i] = 0.f;
    }
    __syncthreads();

    // ---- pin B fragments: wave covers a 32x32 quadrant of the 64x64 z tile ----
    const int wave = tid >> 6, lane = tid & 63, quad = lane >> 4, ln = lane & 15;
    const int mrow0 = (wave >> 1) * 32, ncol0 = (wave & 1) * 32;
    bf16x8 bfrag[2][16];
#pragma unroll
    for (int nt = 0; nt < 2; ++nt)
#pragma unroll
        for (int kt = 0; kt < 16; ++kt)
            bfrag[nt][kt] = *(const bf16x8*)&Abuf[(ncol0 + nt * 16 + ln) * LDA + kt * 32 + quad * 8];
    __syncthreads();

    u64* h1buf = (u64*)(ws + H1_OFF) + (size_t)dir * NSLOT * HSLOT_U64;
    u64* h2buf = (u64*)(ws + H2_OFF) + (size_t)dir * NSLOT * HSLOT_U64;
    u64* hOwn  = (layer == 0) ? h1buf : h2buf;
    float* logits = (float*)(ws + LOG_OFF);
    unsigned* ctrL2 = (unsigned*)ws + dir * 32;

    const int bA = tid >> 2, qA = tid & 3;

    // ---- embed/token software pipeline state (layer 0 only) ----
    float4 pf[16];
    int tokB = 0;
    if (layer == 0) {
        const int tt0 = dir ? (T_LEN - 1) : 0;
        int tokA = tokens[bA * T_LEN + tt0];
        const float4* src = (const float4*)(embed + (size_t)tokA * HID + qA * 64);
#pragma unroll
        for (int j = 0; j < 16; ++j) pf[j] = src[j];
        const int tt1 = dir ? (T_LEN - 2) : 1;
        tokB = tokens[bA * T_LEN + tt1];
    }

    for (int s = 0; s < T_LEN; ++s) {
        // ---- L1 run-ahead throttle (lagging; off critical path in steady state) ----
        if (layer == 0 && tid == 0 && s >= 6) {
            unsigned need = (unsigned)(s - 5) * 16u;
            while (__hip_atomic_load(ctrL2, __ATOMIC_RELAXED, __HIP_MEMORY_SCOPE_AGENT) < need)
                __builtin_amdgcn_s_sleep(1);
        }

        // ---- poll own h (self-validating data; slot s%8 = h_s) ----
        u64 hreg[16];
        poll16(hOwn + (size_t)(s & 7) * HSLOT_U64, tid, hreg);

        // ---- x part ----
        if (layer == 0) {
            uint4* dstx = (uint4*)&Abuf[bA * LDA + qA * 64];
#pragma unroll
            for (int j = 0; j < 8; ++j) dstx[j] = cvt8(&pf[2 * j]);
        } else {
            u64 xreg[16];
            poll16(h1buf + (size_t)((s + 1) & 7) * HSLOT_U64, tid, xreg);   // x(s) = h1_{s+1}
#pragma unroll
            for (int k = 0; k < 16; ++k)
                *(u64*)&Abuf[bA * LDA + k * 16 + qA * 4] = xreg[k];
        }
#pragma unroll
        for (int k = 0; k < 16; ++k)
            *(u64*)&Abuf[bA * LDA + 256 + k * 16 + qA * 4] = hreg[k];
        BARRIER();

        // ---- ordering drain (~free here: every outstanding vmem op is consumed).
        // Completes last step's h-store + poison-clear before this step's stores;
        // guarantees clear(slot X, step s-?) is globally visible before its rewrite.
        asm volatile("s_waitcnt vmcnt(0)" ::: "memory");

        // ---- embed prefetch for s+1: issued AFTER the drain, stays in flight
        // across the raw barriers (no vmcnt drain until consumed next step) ----
        if (layer == 0) {
            const float4* src = (const float4*)(embed + (size_t)tokB * HID + qA * 64);
#pragma unroll
            for (int j = 0; j < 16; ++j) pf[j] = src[j];
            const int sn2 = (s + 2 < T_LEN) ? s + 2 : T_LEN - 1;
            const int tt2 = dir ? (T_LEN - 1 - sn2) : sn2;
            tokB = tokens[bA * T_LEN + tt2];
        }

        // ---- GEMM: z[64x64] = A[64x512] @ Wt^T ----
        f32x4 acc[2][2];
#pragma unroll
        for (int mi = 0; mi < 2; ++mi)
#pragma unroll
            for (int ni = 0; ni < 2; ++ni) acc[mi][ni] = (f32x4)(0.0f);
#pragma unroll
        for (int kt = 0; kt < 16; ++kt) {
            bf16x8 a0 = *(const bf16x8*)&Abuf[(mrow0 + ln) * LDA + kt * 32 + quad * 8];
            bf16x8 a1 = *(const bf16x8*)&Abuf[(mrow0 + 16 + ln) * LDA + kt * 32 + quad * 8];
            acc[0][0] = __builtin_amdgcn_mfma_f32_16x16x32_bf16(a0, bfrag[0][kt], acc[0][0], 0, 0, 0);
            acc[0][1] = __builtin_amdgcn_mfma_f32_16x16x32_bf16(a0, bfrag[1][kt], acc[0][1], 0, 0, 0);
            acc[1][0] = __builtin_amdgcn_mfma_f32_16x16x32_bf16(a1, bfrag[0][kt], acc[1][0], 0, 0, 0);
            acc[1][1] = __builtin_amdgcn_mfma_f32_16x16x32_bf16(a1, bfrag[1][kt], acc[1][1], 0, 0, 0);
        }
#pragma unroll
        for (int mi = 0; mi < 2; ++mi)
#pragma unroll
            for (int ni = 0; ni < 2; ++ni) {
                int row = mrow0 + mi * 16 + quad * 4;
                int col = ncol0 + ni * 16 + ln;
#pragma unroll
                for (int r = 0; r < 4; ++r)
                    zLds[(row + r) * ZLD + col] = acc[mi][ni][r];
            }
        BARRIER();

        // ---- gates: one u64 coherent store + poison-clear of future slot ----
        u64* hdst = hOwn + (size_t)((s + 1) & 7) * HSLOT_U64;
        u64* hclr = hOwn + (size_t)((s + 3) & 7) * HSLOT_U64;
        float hv[4];
        {
            const int b = bA, u0 = qA * 4;
#pragma unroll
            for (int e = 0; e < 4; ++e) {
                int u = u0 + e;
                float zi = zLds[b * ZLD + u]      + bLds[u];
                float zf = zLds[b * ZLD + 16 + u] + bLds[16 + u];
                float zg = zLds[b * ZLD + 32 + u] + bLds[32 + u];
                float zo = zLds[b * ZLD + 48 + u] + bLds[48 + u];
                float ig = 1.f / (1.f + __expf(-zi));
                float fg = 1.f / (1.f + __expf(-zf));
                float gg = 1.f - 2.f / (__expf(2.f * zg) + 1.f);
                float og = 1.f / (1.f + __expf(-zo));
                float cn = fg * cLds[b * 16 + u] + ig * gg;
                cLds[b * 16 + u] = cn;
                hv[e] = og * (1.f - 2.f / (__expf(2.f * cn) + 1.f));
            }
            union { u64 w; bf16 h[4]; } pk;
#pragma unroll
            for (int e = 0; e < 4; ++e) pk.h[e] = (bf16)hv[e];
            __hip_atomic_store(hdst + sub * 256 + tid, pk.w,
                               __ATOMIC_RELAXED, __HIP_MEMORY_SCOPE_AGENT);
            __hip_atomic_store(hclr + sub * 256 + tid, POISON,
                               __ATOMIC_RELAXED, __HIP_MEMORY_SCOPE_AGENT);
        }
        if (layer == 1) {
            float pr[5];
#pragma unroll
            for (int c = 0; c < 5; ++c)
                pr[c] = hv[0] * dwLds[(qA * 4 + 0) * 5 + c] + hv[1] * dwLds[(qA * 4 + 1) * 5 + c]
                      + hv[2] * dwLds[(qA * 4 + 2) * 5 + c] + hv[3] * dwLds[(qA * 4 + 3) * 5 + c];
#pragma unroll
            for (int m = 1; m < 4; m <<= 1)
#pragma unroll
                for (int c = 0; c < 5; ++c) pr[c] += __shfl_xor(pr[c], m);
            if (qA == 0) {
                const int tp = dir ? (T_LEN - 1 - s) : s;
                float* lp = &logits[((size_t)tp * BATCH + bA) * 5];
#pragma unroll
                for (int c = 0; c < 5; ++c) atomicAdd(lp + c, pr[c]);
            }
            // publish group progress (x-consumption of this step is barrier-proven)
            if (tid == 0)
                __hip_atomic_fetch_add(ctrL2, 1u, __ATOMIC_RELAXED, __HIP_MEMORY_SCOPE_AGENT);
        }
        // no end-of-loop barrier needed: next step's A-build (Abuf) is disjoint
        // from gates' reads (zLds/cLds), and B1/B2 of step s+1 order the rest.
    }
}

__global__ void __launch_bounds__(256)
softmax_kernel(const char* __restrict__ ws, const float* __restrict__ dB, float* __restrict__ out)
{
    const int gid = blockIdx.x * 256 + threadIdx.x;
    const int b = gid & 63, t = gid >> 6;
    const float* lp = (const float*)(ws + LOG_OFF) + ((size_t)t * BATCH + b) * 5;
    float l[5];
#pragma unroll
    for (int c = 0; c < 5; ++c) l[c] = lp[c] + dB[c];
    float m = l[0];
#pragma unroll
    for (int c = 1; c < 5; ++c) m = fmaxf(m, l[c]);
    float e[5], ssum = 0.f;
#pragma unroll
    for (int c = 0; c < 5; ++c) { e[c] = __expf(l[c] - m); ssum += e[c]; }
    float inv = 1.f / ssum;
    float* o = out + ((size_t)b * T_LEN + t) * 5;
#pragma unroll
    for (int c = 0; c < 5; ++c) o[c] = e[c] * inv;
}

extern "C" void kernel_launch(void* const* d_in, const int* in_sizes, int n_in,
                              void* d_out, int out_size, void* d_ws, size_t ws_size,
                              hipStream_t stream)
{
    const int*   tokens = (const int*)d_in[0];
    const float* embed  = (const float*)d_in[1];
    const float* W1f = (const float*)d_in[2],  *U1f = (const float*)d_in[3],  *b1f = (const float*)d_in[4];
    const float* W2f = (const float*)d_in[5],  *U2f = (const float*)d_in[6],  *b2f = (const float*)d_in[7];
    const float* W1b = (const float*)d_in[8],  *U1b = (const float*)d_in[9],  *b1b = (const float*)d_in[10];
    const float* W2b = (const float*)d_in[11], *U2b = (const float*)d_in[12], *b2b = (const float*)d_in[13];
    const float* dW  = (const float*)d_in[14], *dB  = (const float*)d_in[15];

    const size_t DIRB = (size_t)NSLOT * HSLOT_U64 * 8;   // per-dir h buffer bytes
    char* w = (char*)d_ws;
    hipMemsetAsync(w, 0, CTRL_BYTES, stream);                      // counters
    hipMemsetAsync(w + H1_OFF, 0xAA, 2 * HBUF_BYTES, stream);      // poison all h slots
    hipMemsetAsync(w + H1_OFF + 0 * DIRB, 0, HSLOT_U64 * 8, stream);   // h1 dir0 slot0 = h_0 = 0
    hipMemsetAsync(w + H1_OFF + 1 * DIRB, 0, HSLOT_U64 * 8, stream);   // h1 dir1 slot0
    hipMemsetAsync(w + H2_OFF + 0 * DIRB, 0, HSLOT_U64 * 8, stream);   // h2 dir0 slot0
    hipMemsetAsync(w + H2_OFF + 1 * DIRB, 0, HSLOT_U64 * 8, stream);   // h2 dir1 slot0
    hipMemsetAsync(w + LOG_OFF, 0, LOG_BYTES, stream);             // logits

    hipFuncSetAttribute(reinterpret_cast<const void*>(lstm_kernel),
                        hipFuncAttributeMaxDynamicSharedMemorySize, SMEM_BYTES);
    lstm_kernel<<<dim3(64), dim3(256), SMEM_BYTES, stream>>>(
        tokens, embed, W1f, U1f, b1f, W2f, U2f, b2f,
        W1b, U1b, b1b, W2b, U2b, b2b, dW, (char*)d_ws);
    softmax_kernel<<<dim3(128), dim3(256), 0, stream>>>((const char*)d_ws, dB, (float*)d_out);
}